// Round 7
// baseline (384.102 us; speedup 1.0000x reference)
//
#include <hip/hip_runtime.h>
#include <hip/hip_bf16.h>

typedef __bf16 bf16x8 __attribute__((ext_vector_type(8)));
typedef __bf16 bf16x4 __attribute__((ext_vector_type(4)));
typedef float  floatx4 __attribute__((ext_vector_type(4)));

#define SH  2097152ll  // per-batch plane: 2048*1024
#define MSH 8388608ll  // full Q/K/V plane: 8192*1024
#define SS  4194304ll  // per-batch score plane: 2048*2048

// Async global->LDS, 16 B per lane. LDS dest is wave-uniform base + lane*16.
#define GLOAD16(gp, lp)                                                        \
  __builtin_amdgcn_global_load_lds(                                            \
      (const __attribute__((address_space(1))) void*)(gp),                     \
      (__attribute__((address_space(3))) void*)(lp), 16, 0, 0)

// ---------------------------------------------------------------------------
// Shared 128x128xBK64 GEMM core: 256 threads = 4 waves, wave w owns the 64x64
// quadrant (rows (w>>1)*64, cols (w&1)*64) as 4x4 16x16x32 bf16 MFMA tiles.
// A: M x K row-major bf16, B: N x K row-major bf16.
// LDS XOR swizzle: logical 16B chunk c of row r is stored at position
// c ^ (r&7). Staging lane ℓ (deposits at ℓ*16) therefore loads global chunk
// (ℓ&7)^(ℓ>>3) — still within the same 128-B line (coalescing preserved) —
// and fragment ds_read_b128s spread over all 8 bank-groups (16-way -> 8-way
// conflicts; SQ_LDS_BANK_CONFLICT was ~768 cyc/block-iter in round 6).
// ---------------------------------------------------------------------------
__device__ __forceinline__ void gemm_core(
    const __bf16* __restrict__ A, const __bf16* __restrict__ B,
    __bf16* As, __bf16* Bs, floatx4 (&acc)[4][4],
    int m0, int n0, int Kd, int lda, int ldb, int tid) {
  const int lane = tid & 63;
  const int w    = tid >> 6;
  const int lo   = lane & 15;
  const int quad = lane >> 4;
  const int lrow  = lane >> 3;                      // 0..7
  const int lcol8 = ((lane & 7) ^ lrow) * 8;        // XOR-swizzled chunk

  const __bf16* aptr = A + (size_t)(m0 + w * 32 + lrow) * lda + lcol8;
  const __bf16* bptr = B + (size_t)(n0 + w * 32 + lrow) * ldb + lcol8;
  __bf16* asl = As + (w * 32) * 64;
  __bf16* bsl = Bs + (w * 32) * 64;

  const int x7 = lo & 7;                            // row&7 for fragment reads

  for (int kk = 0; kk < Kd; kk += 64) {
#pragma unroll
    for (int i = 0; i < 4; i++) {
      GLOAD16(aptr + (size_t)(i * 8) * lda + kk, asl + i * 8 * 64);
      GLOAD16(bptr + (size_t)(i * 8) * ldb + kk, bsl + i * 8 * 64);
    }
    __syncthreads();
#pragma unroll
    for (int kq = 0; kq < 2; kq++) {
      const int pq = ((kq * 4 + quad) ^ x7) * 8;    // physical chunk offset
      bf16x8 af[4], bfq[4];
#pragma unroll
      for (int mt = 0; mt < 4; mt++)
        af[mt] = *(const bf16x8*)&As[((w >> 1) * 64 + mt * 16 + lo) * 64 + pq];
#pragma unroll
      for (int nt = 0; nt < 4; nt++)
        bfq[nt] = *(const bf16x8*)&Bs[((w & 1) * 64 + nt * 16 + lo) * 64 + pq];
#pragma unroll
      for (int mt = 0; mt < 4; mt++)
#pragma unroll
        for (int nt = 0; nt < 4; nt++)
          acc[mt][nt] = __builtin_amdgcn_mfma_f32_16x16x32_bf16(af[mt], bfq[nt], acc[mt][nt], 0, 0, 0);
    }
    __syncthreads();
  }
}

#define GEMM_PRE()                                                             \
  __shared__ __bf16 As[128 * 64];                                              \
  __shared__ __bf16 Bs[128 * 64];                                              \
  const int tid = threadIdx.x;                                                 \
  floatx4 acc[4][4];                                                           \
  _Pragma("unroll") for (int mt = 0; mt < 4; mt++)                             \
      _Pragma("unroll") for (int nt = 0; nt < 4; nt++)                         \
          acc[mt][nt] = (floatx4){0.f, 0.f, 0.f, 0.f};                         \
  const int lane = tid & 63, w = tid >> 6, lo = lane & 15, quad = lane >> 4;   \
  (void)lo; (void)quad;

// QKV projection: [8192 x 3072] = Xb @ Wt[0:3072]^T (+bias). grid (24, 64).
// Epilogue: C/D layout (m89): col = lane&15, row = (lane>>4)*4 + r.
__global__ __launch_bounds__(256) void qkv_k(
    const __bf16* __restrict__ Xb, const __bf16* __restrict__ Wt,
    const float* __restrict__ bq, const float* __restrict__ bk,
    const float* __restrict__ bv, __bf16* __restrict__ QKV) {
  GEMM_PRE();
  const int m0 = blockIdx.y * 128, n0 = blockIdx.x * 128;
  gemm_core(Xb, Wt, As, Bs, acc, m0, n0, 1024, 1024, 1024, tid);
  const int which = n0 >> 10;  // 0=Q 1=K 2=V (block-uniform)
  const float* bp = (which == 0) ? bq : (which == 1) ? bk : bv;
#pragma unroll
  for (int mt = 0; mt < 4; mt++) {
    const int gmb = m0 + (w >> 1) * 64 + mt * 16 + quad * 4;
#pragma unroll
    for (int nt = 0; nt < 4; nt++) {
      const int gnl = (n0 + (w & 1) * 64 + nt * 16 + lo) & 1023;
      const float bv_ = bp[gnl];
#pragma unroll
      for (int r = 0; r < 4; r++)
        QKV[(size_t)which * MSH + (size_t)(gmb + r) * 1024 + gnl] =
            (__bf16)(acc[mt][nt][r] + bv_);
    }
  }
}

// MID: grid (16, 24, 4). by<16 -> scores: E = exp(maskbit ? 1e-20 : QK^T/32)
// (bf16) + rowsum atomics into L. by>=16 -> VWo = V @ Wo, written TRANSPOSED
// (VWoT[e][s], bf16x4-packed along s) for the ctx GEMM's B-operand.
__global__ __launch_bounds__(256) void mid_k(
    const __bf16* __restrict__ QKV, const __bf16* __restrict__ Wt3,
    __bf16* __restrict__ E, __bf16* __restrict__ VWoT,
    const unsigned* __restrict__ Pk, float* __restrict__ L) {
  GEMM_PRE();
  const int bz = blockIdx.z, by = blockIdx.y, bx = blockIdx.x;
  const bool expp = by < 16;
  const __bf16* A = expp ? QKV + bz * SH : QKV + 2 * MSH + bz * SH;
  const __bf16* B = expp ? QKV + MSH + bz * SH : Wt3;
  const int m0 = (expp ? by : bx) * 128;
  const int n0 = (expp ? bx : (by - 16)) * 128;
  gemm_core(A, B, As, Bs, acc, m0, n0, 1024, 1024, 1024, tid);

  if (expp) {
    const unsigned* Pb = Pk + (size_t)bz * 2048 * 64;
#pragma unroll
    for (int mt = 0; mt < 4; mt++) {
      const int gmb = m0 + (w >> 1) * 64 + mt * 16 + quad * 4;
#pragma unroll
      for (int r = 0; r < 4; r++) {
        const int gm = gmb + r;
        float rowpart = 0.f;
#pragma unroll
        for (int nt = 0; nt < 4; nt++) {
          const int gn = n0 + (w & 1) * 64 + nt * 16 + lo;
          const unsigned wd = Pb[(size_t)gm * 64 + (gn >> 5)];
          float s = acc[mt][nt][r] * 0.03125f;
          if ((wd >> (gn & 31)) & 1u) s = 1e-20f;
          const float e = __expf(s);
          rowpart += e;
          E[(size_t)bz * SS + (size_t)gm * 2048 + gn] = (__bf16)e;
        }
        rowpart += __shfl_xor(rowpart, 1);
        rowpart += __shfl_xor(rowpart, 2);
        rowpart += __shfl_xor(rowpart, 4);
        rowpart += __shfl_xor(rowpart, 8);
        if (lo == 0) atomicAdd(&L[(size_t)bz * 2048 + gm], rowpart);
      }
    }
  } else {
#pragma unroll
    for (int mt = 0; mt < 4; mt++) {
      const int gmb = m0 + (w >> 1) * 64 + mt * 16 + quad * 4;  // s index
#pragma unroll
      for (int nt = 0; nt < 4; nt++) {
        const int gn = n0 + (w & 1) * 64 + nt * 16 + lo;        // e index
        bf16x4 pk;
#pragma unroll
        for (int r = 0; r < 4; r++) pk[r] = (__bf16)acc[mt][nt][r];
        *(bf16x4*)(VWoT + (size_t)bz * SH + (size_t)gn * 2048 + gmb) = pk;
      }
    }
  }
}

// CTX/OUT fused, split-K2: out += (E[:,ks*1024:+1024] @ VWoT^T chunk) / L
// (+bo from the ks==0 half). d_out zeroed in prep; fp32 atomicAdd.
// grid (8, 16, 8): bz = z>>1, ks = z&1.
__global__ __launch_bounds__(256) void ctx_k(
    const __bf16* __restrict__ E, const __bf16* __restrict__ VWoT,
    const float* __restrict__ L, const float* __restrict__ bo,
    float* __restrict__ out) {
  GEMM_PRE();
  const int bz = blockIdx.z >> 1, ks = blockIdx.z & 1;
  const int m0 = blockIdx.y * 128, n0 = blockIdx.x * 128;
  gemm_core(E + (size_t)bz * SS + ks * 1024,
            VWoT + (size_t)bz * SH + ks * 1024, As, Bs, acc,
            m0, n0, 1024, 2048, 2048, tid);
#pragma unroll
  for (int mt = 0; mt < 4; mt++) {
    const int gmb = m0 + (w >> 1) * 64 + mt * 16 + quad * 4;
#pragma unroll
    for (int nt = 0; nt < 4; nt++) {
      const int gn = n0 + (w & 1) * 64 + nt * 16 + lo;
      const float bo_ = ks ? 0.f : bo[gn];
#pragma unroll
      for (int r = 0; r < 4; r++) {
        const int gm = gmb + r;
        const float inv = 1.0f / L[(size_t)bz * 2048 + gm];
        atomicAdd(&out[((size_t)bz * 2048 + gm) * 1024 + gn],
                  acc[mt][nt][r] * inv + bo_);
      }
    }
  }
}

// Prep, grid (16,16,7):
//   z=0..3 : transpose+convert W[z] (1024x1024 fp32 K x N) -> bf16 N x K.
//   z=4    : convert fp32 X -> bf16; zero L (first 32 blocks).
//   z=5    : pack int32 mask (4*2048*2048) -> bitmask Pk (524288 u32).
//   z=6    : zero d_out (8.4M fp32) for ctx's atomic accumulation.
__global__ __launch_bounds__(256) void prep_k(
    const float* __restrict__ X, __bf16* __restrict__ Xb,
    const float* __restrict__ Wq, const float* __restrict__ Wk,
    const float* __restrict__ Wv, const float* __restrict__ Wo,
    __bf16* __restrict__ Wt, float* __restrict__ L,
    const int* __restrict__ mask, unsigned* __restrict__ Pk,
    float* __restrict__ out) {
  const int z = blockIdx.z;
  const int tid = threadIdx.x;
  const int bid = blockIdx.y * 16 + blockIdx.x;  // 0..255
  if (z == 4) {
    if (bid < 32) L[bid * 256 + tid] = 0.f;
#pragma unroll
    for (int k = 0; k < 32; k++) {
      const size_t i = (size_t)(bid * 256 + tid) + (size_t)k * 65536;
      const float4 v = ((const float4*)X)[i];
      bf16x4 o;
      o[0] = (__bf16)v.x; o[1] = (__bf16)v.y; o[2] = (__bf16)v.z; o[3] = (__bf16)v.w;
      ((bf16x4*)Xb)[i] = o;
    }
    return;
  }
  if (z == 5) {
#pragma unroll
    for (int k = 0; k < 8; k++) {
      const int idx = bid * 256 + tid + k * 65536;
      const int4* m4 = (const int4*)(mask + (size_t)idx * 32);
      unsigned bits = 0;
#pragma unroll
      for (int q = 0; q < 8; q++) {
        int4 v = m4[q];
        bits |= (v.x != 0 ? 1u : 0u) << (q * 4);
        bits |= (v.y != 0 ? 1u : 0u) << (q * 4 + 1);
        bits |= (v.z != 0 ? 1u : 0u) << (q * 4 + 2);
        bits |= (v.w != 0 ? 1u : 0u) << (q * 4 + 3);
      }
      Pk[idx] = bits;
    }
    return;
  }
  if (z == 6) {
    float4* o4 = (float4*)out;
#pragma unroll
    for (int k = 0; k < 32; k++)
      o4[(size_t)(bid * 256 + tid) + (size_t)k * 65536] = (float4){0.f, 0.f, 0.f, 0.f};
    return;
  }
  const float* W = (z == 0) ? Wq : (z == 1) ? Wk : (z == 2) ? Wv : Wo;
  __bf16* D = Wt + (size_t)z * 1024 * 1024;
  __shared__ float T[64][65];
  const int r0 = blockIdx.y * 64, c0 = blockIdx.x * 64;
#pragma unroll
  for (int i = 0; i < 16; i++) {
    const int e = i * 256 + tid;
    const int r = e >> 6, c = e & 63;
    T[r][c] = W[(size_t)(r0 + r) * 1024 + c0 + c];
  }
  __syncthreads();
#pragma unroll
  for (int i = 0; i < 16; i++) {
    const int e = i * 256 + tid;
    const int rr = e >> 6, cc = e & 63;
    D[(size_t)(c0 + rr) * 1024 + r0 + cc] = (__bf16)T[cc][rr];
  }
}

extern "C" void kernel_launch(void* const* d_in, const int* in_sizes, int n_in,
                              void* d_out, int out_size, void* d_ws, size_t ws_size,
                              hipStream_t stream) {
  (void)in_sizes; (void)n_in; (void)out_size; (void)ws_size;
  const int H = 1024;
  const long long MS = 8192;

  const float* X   = (const float*)d_in[0];
  const int*   msk = (const int*)d_in[1];
  const float* Wq  = (const float*)d_in[2];
  const float* bq  = (const float*)d_in[3];
  const float* Wk  = (const float*)d_in[4];
  const float* bk  = (const float*)d_in[5];
  const float* Wv  = (const float*)d_in[6];
  const float* bv  = (const float*)d_in[7];
  const float* Wo  = (const float*)d_in[8];
  const float* bo  = (const float*)d_in[9];
  float* out = (float*)d_out;

  // Workspace (~111.3 MB):
  //   Xb[16.8M] Wt[8.4M] QKV[50.3M] E[33.6M bf16] L[32K] Pk[2.1M]
  //   VWoT (16.8M) aliases Xb (dead after QKV projection).
  char* ws = (char*)d_ws;
  __bf16* Xb  = (__bf16*)ws;
  __bf16* Wt  = Xb + (size_t)MS * H;
  __bf16* QKV = Wt + (size_t)4 * H * H;
  __bf16* E   = QKV + (size_t)3 * MS * H;
  float*  L   = (float*)(E + (size_t)4 * SS);
  unsigned* Pk = (unsigned*)(L + 8192);
  __bf16* VWoT = Xb;  // alias

  dim3 blk(256);

  prep_k<<<dim3(16, 16, 7), blk, 0, stream>>>(X, Xb, Wq, Wk, Wv, Wo, Wt, L, msk, Pk, out);
  qkv_k<<<dim3(24, 64), blk, 0, stream>>>(Xb, Wt, bq, bk, bv, QKV);
  mid_k<<<dim3(16, 24, 4), blk, 0, stream>>>(QKV, Wt + (size_t)3 * H * H, E, VWoT, Pk, L);
  ctx_k<<<dim3(8, 16, 8), blk, 0, stream>>>(E, VWoT, L, bo, out);
}

// Round 8
// 342.254 us; speedup vs baseline: 1.1223x; 1.1223x over previous
//
#include <hip/hip_runtime.h>
#include <hip/hip_bf16.h>

typedef __bf16 bf16x8 __attribute__((ext_vector_type(8)));
typedef __bf16 bf16x4 __attribute__((ext_vector_type(4)));
typedef float  floatx4 __attribute__((ext_vector_type(4)));

#define SH  2097152ll  // per-batch plane: 2048*1024
#define MSH 8388608ll  // full Q/K/V plane: 8192*1024
#define SS  4194304ll  // per-batch score plane: 2048*2048

// Async global->LDS, 16 B per lane. LDS dest is wave-uniform base + lane*16.
#define GLOAD16(gp, lp)                                                        \
  __builtin_amdgcn_global_load_lds(                                            \
      (const __attribute__((address_space(1))) void*)(gp),                     \
      (__attribute__((address_space(3))) void*)(lp), 16, 0, 0)

// ---------------------------------------------------------------------------
// Shared 128x128xBK64 GEMM core: 256 threads = 4 waves, wave w owns the 64x64
// quadrant (rows (w>>1)*64, cols (w&1)*64) as 4x4 16x16x32 bf16 MFMA tiles.
// A: M x K row-major bf16, B: N x K row-major bf16.
// LDS XOR swizzle (round 7: SQ_LDS_BANK_CONFLICT 1.9e7 -> 0, mid 106->90us):
// logical 16B chunk c of row r stored at c ^ (r&7); staging lane loads global
// chunk (lane&7)^(lane>>3) (same 128-B line -> coalescing preserved).
// ---------------------------------------------------------------------------
__device__ __forceinline__ void gemm_core(
    const __bf16* __restrict__ A, const __bf16* __restrict__ B,
    __bf16* As, __bf16* Bs, floatx4 (&acc)[4][4],
    int m0, int n0, int Kd, int lda, int ldb, int tid) {
  const int lane = tid & 63;
  const int w    = tid >> 6;
  const int lo   = lane & 15;
  const int quad = lane >> 4;
  const int lrow  = lane >> 3;                      // 0..7
  const int lcol8 = ((lane & 7) ^ lrow) * 8;        // XOR-swizzled chunk

  const __bf16* aptr = A + (size_t)(m0 + w * 32 + lrow) * lda + lcol8;
  const __bf16* bptr = B + (size_t)(n0 + w * 32 + lrow) * ldb + lcol8;
  __bf16* asl = As + (w * 32) * 64;
  __bf16* bsl = Bs + (w * 32) * 64;

  const int x7 = lo & 7;                            // row&7 for fragment reads

  for (int kk = 0; kk < Kd; kk += 64) {
#pragma unroll
    for (int i = 0; i < 4; i++) {
      GLOAD16(aptr + (size_t)(i * 8) * lda + kk, asl + i * 8 * 64);
      GLOAD16(bptr + (size_t)(i * 8) * ldb + kk, bsl + i * 8 * 64);
    }
    __syncthreads();
#pragma unroll
    for (int kq = 0; kq < 2; kq++) {
      const int pq = ((kq * 4 + quad) ^ x7) * 8;    // physical chunk offset
      bf16x8 af[4], bfq[4];
#pragma unroll
      for (int mt = 0; mt < 4; mt++)
        af[mt] = *(const bf16x8*)&As[((w >> 1) * 64 + mt * 16 + lo) * 64 + pq];
#pragma unroll
      for (int nt = 0; nt < 4; nt++)
        bfq[nt] = *(const bf16x8*)&Bs[((w & 1) * 64 + nt * 16 + lo) * 64 + pq];
#pragma unroll
      for (int mt = 0; mt < 4; mt++)
#pragma unroll
        for (int nt = 0; nt < 4; nt++)
          acc[mt][nt] = __builtin_amdgcn_mfma_f32_16x16x32_bf16(af[mt], bfq[nt], acc[mt][nt], 0, 0, 0);
    }
    __syncthreads();
  }
}

#define GEMM_PRE()                                                             \
  __shared__ __bf16 As[128 * 64];                                              \
  __shared__ __bf16 Bs[128 * 64];                                              \
  const int tid = threadIdx.x;                                                 \
  floatx4 acc[4][4];                                                           \
  _Pragma("unroll") for (int mt = 0; mt < 4; mt++)                             \
      _Pragma("unroll") for (int nt = 0; nt < 4; nt++)                         \
          acc[mt][nt] = (floatx4){0.f, 0.f, 0.f, 0.f};                         \
  const int lane = tid & 63, w = tid >> 6, lo = lane & 15, quad = lane >> 4;   \
  (void)lo; (void)quad;

// QKV projection: [8192 x 3072] = Xb @ Wt[0:3072]^T (+bias). grid (24, 64).
// Epilogue: C/D layout (m89): col = lane&15, row = (lane>>4)*4 + r.
__global__ __launch_bounds__(256) void qkv_k(
    const __bf16* __restrict__ Xb, const __bf16* __restrict__ Wt,
    const float* __restrict__ bq, const float* __restrict__ bk,
    const float* __restrict__ bv, __bf16* __restrict__ QKV) {
  GEMM_PRE();
  const int m0 = blockIdx.y * 128, n0 = blockIdx.x * 128;
  gemm_core(Xb, Wt, As, Bs, acc, m0, n0, 1024, 1024, 1024, tid);
  const int which = n0 >> 10;  // 0=Q 1=K 2=V (block-uniform)
  const float* bp = (which == 0) ? bq : (which == 1) ? bk : bv;
#pragma unroll
  for (int mt = 0; mt < 4; mt++) {
    const int gmb = m0 + (w >> 1) * 64 + mt * 16 + quad * 4;
#pragma unroll
    for (int nt = 0; nt < 4; nt++) {
      const int gnl = (n0 + (w & 1) * 64 + nt * 16 + lo) & 1023;
      const float bv_ = bp[gnl];
#pragma unroll
      for (int r = 0; r < 4; r++)
        QKV[(size_t)which * MSH + (size_t)(gmb + r) * 1024 + gnl] =
            (__bf16)(acc[mt][nt][r] + bv_);
    }
  }
}

// MID: grid (384, 1, 4), XCD-aware tile decode. Under round-robin wg->XCD
// (id%8), XCD x owns: exp tiles by∈[(x>>1)*4,+4) x bx∈[(x&1)*8,+8)  (A 1MB +
// B 2MB fits the 4MiB private L2; round-7 mapping needed ~4.7MB -> thrashed,
// FETCH 125MB vs ~52 ideal), plus vwo tiles (4x4 patch).
// exp  : E = exp(maskbit ? 1e-20 : QK^T/32) bf16 + rowsum atomics into L.
// vwo  : VWo = V @ Wo written TRANSPOSED (VWoT[e][s], bf16x4 along s).
__global__ __launch_bounds__(256) void mid_k(
    const __bf16* __restrict__ QKV, const __bf16* __restrict__ Wt3,
    __bf16* __restrict__ E, __bf16* __restrict__ VWoT,
    const unsigned* __restrict__ Pk, float* __restrict__ L) {
  GEMM_PRE();
  const int bz = blockIdx.z;
  const int sid = blockIdx.x;
  const int xcd = sid & 7, kk = sid >> 3;  // kk 0..47
  const bool expp = kk < 32;
  int m0, n0;
  if (expp) {
    m0 = ((xcd >> 1) * 4 + (kk >> 3)) * 128;   // by 0..15
    n0 = ((xcd & 1) * 8 + (kk & 7)) * 128;     // bx 0..15
  } else {
    const int k2 = kk - 32;                     // 0..15
    m0 = ((xcd >> 1) * 4 + (k2 >> 2)) * 128;   // s-tile 0..15
    n0 = ((xcd & 1) * 4 + (k2 & 3)) * 128;     // e-tile 0..7
  }
  const __bf16* A = expp ? QKV + bz * SH : QKV + 2 * MSH + bz * SH;
  const __bf16* B = expp ? QKV + MSH + bz * SH : Wt3;
  gemm_core(A, B, As, Bs, acc, m0, n0, 1024, 1024, 1024, tid);

  if (expp) {
    const unsigned* Pb = Pk + (size_t)bz * 2048 * 64;
#pragma unroll
    for (int mt = 0; mt < 4; mt++) {
      const int gmb = m0 + (w >> 1) * 64 + mt * 16 + quad * 4;
#pragma unroll
      for (int r = 0; r < 4; r++) {
        const int gm = gmb + r;
        float rowpart = 0.f;
#pragma unroll
        for (int nt = 0; nt < 4; nt++) {
          const int gn = n0 + (w & 1) * 64 + nt * 16 + lo;
          const unsigned wd = Pb[(size_t)gm * 64 + (gn >> 5)];
          float s = acc[mt][nt][r] * 0.03125f;
          if ((wd >> (gn & 31)) & 1u) s = 1e-20f;
          const float e = __expf(s);
          rowpart += e;
          E[(size_t)bz * SS + (size_t)gm * 2048 + gn] = (__bf16)e;
        }
        rowpart += __shfl_xor(rowpart, 1);
        rowpart += __shfl_xor(rowpart, 2);
        rowpart += __shfl_xor(rowpart, 4);
        rowpart += __shfl_xor(rowpart, 8);
        if (lo == 0) atomicAdd(&L[(size_t)bz * 2048 + gm], rowpart);
      }
    }
  } else {
#pragma unroll
    for (int mt = 0; mt < 4; mt++) {
      const int gmb = m0 + (w >> 1) * 64 + mt * 16 + quad * 4;  // s index
#pragma unroll
      for (int nt = 0; nt < 4; nt++) {
        const int gn = n0 + (w & 1) * 64 + nt * 16 + lo;        // e index
        bf16x4 pk;
#pragma unroll
        for (int r = 0; r < 4; r++) pk[r] = (__bf16)acc[mt][nt][r];
        *(bf16x4*)(VWoT + (size_t)bz * SH + (size_t)gn * 2048 + gmb) = pk;
      }
    }
  }
}

// CTX/OUT fused: out = (E @ VWoT^T) / L + bo -> fp32. grid (8, 16, 4).
// (Round-7 split-K2 atomicAdd variant REGRESSED — direct store restored.)
__global__ __launch_bounds__(256) void ctx_k(
    const __bf16* __restrict__ E, const __bf16* __restrict__ VWoT,
    const float* __restrict__ L, const float* __restrict__ bo,
    float* __restrict__ out) {
  GEMM_PRE();
  const int bz = blockIdx.z;
  const int m0 = blockIdx.y * 128, n0 = blockIdx.x * 128;
  gemm_core(E + (size_t)bz * SS, VWoT + (size_t)bz * SH, As, Bs, acc,
            m0, n0, 2048, 2048, 2048, tid);
#pragma unroll
  for (int mt = 0; mt < 4; mt++) {
    const int gmb = m0 + (w >> 1) * 64 + mt * 16 + quad * 4;
#pragma unroll
    for (int nt = 0; nt < 4; nt++) {
      const int gn = n0 + (w & 1) * 64 + nt * 16 + lo;
      const float bo_ = bo[gn];
#pragma unroll
      for (int r = 0; r < 4; r++) {
        const int gm = gmb + r;
        const float inv = 1.0f / L[(size_t)bz * 2048 + gm];
        out[((size_t)bz * 2048 + gm) * 1024 + gn] = acc[mt][nt][r] * inv + bo_;
      }
    }
  }
}

// Prep, grid (16,16,9):
//   z=0..3 : transpose+convert W[z] (1024x1024 fp32 K x N) -> bf16 N x K.
//   z=4    : convert fp32 X -> bf16; zero L (first 32 blocks).
//   z=5..8 : pack int32 mask (4*2048*2048) -> bitmask Pk, one quarter per
//            z-plane (4x the blocks of round 7's single-plane pack).
__global__ __launch_bounds__(256) void prep_k(
    const float* __restrict__ X, __bf16* __restrict__ Xb,
    const float* __restrict__ Wq, const float* __restrict__ Wk,
    const float* __restrict__ Wv, const float* __restrict__ Wo,
    __bf16* __restrict__ Wt, float* __restrict__ L,
    const int* __restrict__ mask, unsigned* __restrict__ Pk) {
  const int z = blockIdx.z;
  const int tid = threadIdx.x;
  const int bid = blockIdx.y * 16 + blockIdx.x;  // 0..255
  if (z == 4) {
    if (bid < 32) L[bid * 256 + tid] = 0.f;
#pragma unroll
    for (int k = 0; k < 32; k++) {
      const size_t i = (size_t)(bid * 256 + tid) + (size_t)k * 65536;
      const float4 v = ((const float4*)X)[i];
      bf16x4 o;
      o[0] = (__bf16)v.x; o[1] = (__bf16)v.y; o[2] = (__bf16)v.z; o[3] = (__bf16)v.w;
      ((bf16x4*)Xb)[i] = o;
    }
    return;
  }
  if (z >= 5) {
    const int base = (z - 5) * 131072;  // u32 words per quarter
#pragma unroll
    for (int k = 0; k < 2; k++) {
      const int idx = base + bid * 512 + k * 256 + tid;
      const int4* m4 = (const int4*)(mask + (size_t)idx * 32);
      unsigned bits = 0;
#pragma unroll
      for (int q = 0; q < 8; q++) {
        int4 v = m4[q];
        bits |= (v.x != 0 ? 1u : 0u) << (q * 4);
        bits |= (v.y != 0 ? 1u : 0u) << (q * 4 + 1);
        bits |= (v.z != 0 ? 1u : 0u) << (q * 4 + 2);
        bits |= (v.w != 0 ? 1u : 0u) << (q * 4 + 3);
      }
      Pk[idx] = bits;
    }
    return;
  }
  const float* W = (z == 0) ? Wq : (z == 1) ? Wk : (z == 2) ? Wv : Wo;
  __bf16* D = Wt + (size_t)z * 1024 * 1024;
  __shared__ float T[64][65];
  const int r0 = blockIdx.y * 64, c0 = blockIdx.x * 64;
#pragma unroll
  for (int i = 0; i < 16; i++) {
    const int e = i * 256 + tid;
    const int r = e >> 6, c = e & 63;
    T[r][c] = W[(size_t)(r0 + r) * 1024 + c0 + c];
  }
  __syncthreads();
#pragma unroll
  for (int i = 0; i < 16; i++) {
    const int e = i * 256 + tid;
    const int rr = e >> 6, cc = e & 63;
    D[(size_t)(c0 + rr) * 1024 + r0 + cc] = (__bf16)T[cc][rr];
  }
}

extern "C" void kernel_launch(void* const* d_in, const int* in_sizes, int n_in,
                              void* d_out, int out_size, void* d_ws, size_t ws_size,
                              hipStream_t stream) {
  (void)in_sizes; (void)n_in; (void)out_size; (void)ws_size;
  const int H = 1024;
  const long long MS = 8192;

  const float* X   = (const float*)d_in[0];
  const int*   msk = (const int*)d_in[1];
  const float* Wq  = (const float*)d_in[2];
  const float* bq  = (const float*)d_in[3];
  const float* Wk  = (const float*)d_in[4];
  const float* bk  = (const float*)d_in[5];
  const float* Wv  = (const float*)d_in[6];
  const float* bv  = (const float*)d_in[7];
  const float* Wo  = (const float*)d_in[8];
  const float* bo  = (const float*)d_in[9];
  float* out = (float*)d_out;

  // Workspace (~111.3 MB):
  //   Xb[16.8M] Wt[8.4M] QKV[50.3M] E[33.6M bf16] L[32K] Pk[2.1M]
  //   VWoT (16.8M) aliases Xb (dead after QKV projection).
  char* ws = (char*)d_ws;
  __bf16* Xb  = (__bf16*)ws;
  __bf16* Wt  = Xb + (size_t)MS * H;
  __bf16* QKV = Wt + (size_t)4 * H * H;
  __bf16* E   = QKV + (size_t)3 * MS * H;
  float*  L   = (float*)(E + (size_t)4 * SS);
  unsigned* Pk = (unsigned*)(L + 8192);
  __bf16* VWoT = Xb;  // alias

  dim3 blk(256);

  prep_k<<<dim3(16, 16, 9), blk, 0, stream>>>(X, Xb, Wq, Wk, Wv, Wo, Wt, L, msk, Pk);
  qkv_k<<<dim3(24, 64), blk, 0, stream>>>(Xb, Wt, bq, bk, bv, QKV);
  mid_k<<<dim3(384, 1, 4), blk, 0, stream>>>(QKV, Wt + (size_t)3 * H * H, E, VWoT, Pk, L);
  ctx_k<<<dim3(8, 16, 4), blk, 0, stream>>>(E, VWoT, L, bo, out);
}